// Round 1
// baseline (4948.214 us; speedup 1.0000x reference)
//
#include <hip/hip_runtime.h>

// ---------------------------------------------------------------------------
// GCN forward: 3x (GEMM -> self-loop-init -> edge scatter-add), mean-pool, linear
// Layout: all feature matrices [N,128] row-major fp32.
// ---------------------------------------------------------------------------

__global__ __launch_bounds__(256) void count_deg_kernel(const int* __restrict__ col,
                                                        float* __restrict__ deg, int E) {
    int e = blockIdx.x * 256 + threadIdx.x;
    if (e < E) atomicAdd(&deg[col[e]], 1.0f);
}

__global__ __launch_bounds__(256) void dinv_kernel(float* __restrict__ deg, int N) {
    int n = blockIdx.x * 256 + threadIdx.x;
    if (n < N) deg[n] = 1.0f / sqrtf(deg[n] + 1.0f);  // +1 = self loop
}

// T[N,128] = act(H[N,128]) @ W[128,128]; act = relu if applyRelu (deferred relu)
__global__ __launch_bounds__(256) void gemm128_kernel(const float* __restrict__ H,
                                                      const float* __restrict__ W,
                                                      float* __restrict__ T,
                                                      int N, int applyRelu) {
    __shared__ float Ws[64 * 128];   // 32 KB: one k-half of W
    __shared__ float xs[32 * 132];   // 16.9 KB: 32 rows, stride 132 (=33*16B, 4-aligned, bank-safe)
    const int tid = threadIdx.x;
    const int row0 = blockIdx.x * 32;

    // stage 32 rows of H (full 128 cols), relu on load if requested
    {
        const float4* H4 = (const float4*)H;
        #pragma unroll
        for (int i = 0; i < 4; ++i) {
            int lin = tid + i * 256;   // float4 slot index, 1024 total
            int r = lin >> 5;          // 32 float4 per row
            int k4 = lin & 31;
            int gr = row0 + r;
            float4 v = make_float4(0.f, 0.f, 0.f, 0.f);
            if (gr < N) v = H4[(size_t)gr * 32 + k4];
            if (applyRelu) {
                v.x = fmaxf(v.x, 0.f); v.y = fmaxf(v.y, 0.f);
                v.z = fmaxf(v.z, 0.f); v.w = fmaxf(v.w, 0.f);
            }
            *(float4*)&xs[r * 132 + k4 * 4] = v;
        }
    }

    const int ct = tid & 31;   // col group 0..31 -> cols c..c+3
    const int rt = tid >> 5;   // row group 0..7  -> rows r0..r0+3
    const int c = ct * 4;
    const int r0 = rt * 4;
    float acc[4][4];
    #pragma unroll
    for (int i = 0; i < 4; ++i)
        #pragma unroll
        for (int j = 0; j < 4; ++j) acc[i][j] = 0.f;

    for (int p = 0; p < 2; ++p) {
        __syncthreads();
        {   // load W rows [64p, 64p+64): 2048 float4 = 8/thread
            const float4* W4 = (const float4*)(W + p * 64 * 128);
            float4* Ws4 = (float4*)Ws;
            #pragma unroll
            for (int i = 0; i < 8; ++i) Ws4[tid + i * 256] = W4[tid + i * 256];
        }
        __syncthreads();
        const int kbase = p * 64;
        #pragma unroll 4
        for (int k = 0; k < 64; k += 4) {
            float4 xv[4];
            #pragma unroll
            for (int i = 0; i < 4; ++i)
                xv[i] = *(const float4*)&xs[(r0 + i) * 132 + kbase + k];
            #pragma unroll
            for (int kk = 0; kk < 4; ++kk) {
                float4 wv = *(const float4*)&Ws[(k + kk) * 128 + c];
                #pragma unroll
                for (int i = 0; i < 4; ++i) {
                    float xk = (kk == 0) ? xv[i].x : (kk == 1) ? xv[i].y
                             : (kk == 2) ? xv[i].z : xv[i].w;
                    acc[i][0] = fmaf(xk, wv.x, acc[i][0]);
                    acc[i][1] = fmaf(xk, wv.y, acc[i][1]);
                    acc[i][2] = fmaf(xk, wv.z, acc[i][2]);
                    acc[i][3] = fmaf(xk, wv.w, acc[i][3]);
                }
            }
        }
    }
    #pragma unroll
    for (int i = 0; i < 4; ++i) {
        int gr = row0 + r0 + i;
        if (gr < N)
            *(float4*)&T[(size_t)gr * 128 + c] =
                make_float4(acc[i][0], acc[i][1], acc[i][2], acc[i][3]);
    }
}

// B[n,:] = dinv[n]^2 * A[n,:] + bias  (self-loop message + bias; agg init)
__global__ __launch_bounds__(256) void init_agg_kernel(const float* __restrict__ A,
                                                       const float* __restrict__ dinv,
                                                       const float* __restrict__ bias,
                                                       float* __restrict__ B, int N) {
    int tid = blockIdx.x * 256 + threadIdx.x;  // N*32 float4 units
    int n = tid >> 5;
    if (n >= N) return;
    int k4 = tid & 31;
    float d = dinv[n];
    float d2 = d * d;
    float4 v = ((const float4*)A)[tid];
    float4 bv = ((const float4*)bias)[k4];
    float4 o;
    o.x = fmaf(d2, v.x, bv.x);
    o.y = fmaf(d2, v.y, bv.y);
    o.z = fmaf(d2, v.z, bv.z);
    o.w = fmaf(d2, v.w, bv.w);
    ((float4*)B)[tid] = o;
}

// per edge e: B[col[e],:] += dinv[row]*dinv[col] * A[row[e],:]
__global__ __launch_bounds__(256) void scatter_kernel(const int* __restrict__ ei,
                                                      const float* __restrict__ dinv,
                                                      const float* __restrict__ A,
                                                      float* __restrict__ B, int E) {
    int tid = blockIdx.x * 256 + threadIdx.x;
    int e = tid >> 6;          // 64 lanes per edge, 2 floats per lane
    if (e >= E) return;
    int lane = tid & 63;
    int r = ei[e];
    int c = ei[E + e];
    float nrm = dinv[r] * dinv[c];
    float2 v = ((const float2*)(A + (size_t)r * 128))[lane];
    float* Bc = B + (size_t)c * 128 + lane * 2;
    atomicAdd(Bc,     nrm * v.x);
    atomicAdd(Bc + 1, nrm * v.y);
}

// pooled[g,:] += relu(H[n,:]); cnt[g] += 1
__global__ __launch_bounds__(256) void pool_kernel(const float* __restrict__ H,
                                                   const int* __restrict__ batch,
                                                   float* __restrict__ pooled,
                                                   float* __restrict__ cnt, int N) {
    int tid = blockIdx.x * 256 + threadIdx.x;
    int n = tid >> 6;
    if (n >= N) return;
    int lane = tid & 63;
    int g = batch[n];
    float2 v = ((const float2*)(H + (size_t)n * 128))[lane];
    atomicAdd(&pooled[g * 128 + lane * 2],     fmaxf(v.x, 0.f));
    atomicAdd(&pooled[g * 128 + lane * 2 + 1], fmaxf(v.y, 0.f));
    if (lane == 0) atomicAdd(&cnt[g], 1.0f);
}

// out[g] = dot(pooled[g]/max(cnt,1), lin_w) + lin_b
__global__ __launch_bounds__(128) void final_kernel(const float* __restrict__ pooled,
                                                    const float* __restrict__ cnt,
                                                    const float* __restrict__ lin_w,
                                                    const float* __restrict__ lin_b,
                                                    float* __restrict__ out) {
    __shared__ float red[128];
    int g = blockIdx.x, f = threadIdx.x;
    red[f] = pooled[g * 128 + f] * lin_w[f];
    __syncthreads();
    for (int s = 64; s > 0; s >>= 1) {
        if (f < s) red[f] += red[f + s];
        __syncthreads();
    }
    if (f == 0) out[g] = red[0] / fmaxf(cnt[g], 1.0f) + lin_b[0];
}

extern "C" void kernel_launch(void* const* d_in, const int* in_sizes, int n_in,
                              void* d_out, int out_size, void* d_ws, size_t ws_size,
                              hipStream_t stream) {
    const float* x     = (const float*)d_in[0];
    const int*   ei    = (const int*)d_in[1];    // [2,E]: rows then cols
    const int*   batch = (const int*)d_in[2];
    const float* W1    = (const float*)d_in[3];
    const float* b1    = (const float*)d_in[4];
    const float* W2    = (const float*)d_in[5];
    const float* b2    = (const float*)d_in[6];
    const float* W3    = (const float*)d_in[7];
    const float* b3    = (const float*)d_in[8];
    const float* lin_w = (const float*)d_in[9];
    const float* lin_b = (const float*)d_in[10];
    float* out = (float*)d_out;

    const int N = in_sizes[0] / 128;
    const int E = in_sizes[1] / 2;
    const int G = out_size;

    // workspace carve-up (floats): A | B | dinv | pooled | cnt  (~103 MB)
    float* A      = (float*)d_ws;
    float* B      = A + (size_t)N * 128;
    float* dinv   = B + (size_t)N * 128;
    float* pooled = dinv + N;
    float* cnt    = pooled + (size_t)G * 128;

    // degree -> dinv (deg stored in dinv buffer, transformed in place)
    hipMemsetAsync(dinv, 0, (size_t)N * sizeof(float), stream);
    count_deg_kernel<<<(E + 255) / 256, 256, 0, stream>>>(ei + E, dinv, E);
    dinv_kernel<<<(N + 255) / 256, 256, 0, stream>>>(dinv, N);

    const float* Ws[3] = {W1, W2, W3};
    const float* bs[3] = {b1, b2, b3};
    for (int l = 0; l < 3; ++l) {
        // A = act(prev) @ W   (prev = x for layer 0, else B holding pre-relu h)
        gemm128_kernel<<<(N + 31) / 32, 256, 0, stream>>>(l == 0 ? x : B, Ws[l], A, N,
                                                          l == 0 ? 0 : 1);
        // B = dinv^2 * A + b  (self-loop + bias)
        init_agg_kernel<<<(N * 32 + 255) / 256, 256, 0, stream>>>(A, dinv, bs[l], B, N);
        // B += scatter of normalized neighbor messages
        scatter_kernel<<<(E * 64 + 255) / 256, 256, 0, stream>>>(ei, dinv, A, B, E);
        // relu deferred: consumers (next gemm / pool) apply max(0, .) on load
    }

    hipMemsetAsync(pooled, 0, (size_t)(G * 128 + G) * sizeof(float), stream);
    pool_kernel<<<(N * 64 + 255) / 256, 256, 0, stream>>>(B, batch, pooled, cnt, N);
    final_kernel<<<G, 128, 0, stream>>>(pooled, cnt, lin_w, lin_b, out);
}

// Round 2
// 1113.643 us; speedup vs baseline: 4.4433x; 4.4433x over previous
//
#include <hip/hip_runtime.h>

// ---------------------------------------------------------------------------
// GCN forward, CSR-sorted aggregation (no atomics in hot path):
//   build: deg count -> prefix sum (rowptr) -> counting-sort fill (src_sorted)
//   3x: GEMM (fp32, LDS-tiled) -> agg (wave/node gather, fused self-loop+bias)
//   fused pool+linear head over sorted batch (segmented reduce)
// All feature matrices [N,128] row-major fp32.
// ---------------------------------------------------------------------------

__global__ __launch_bounds__(256) void count_deg_kernel(const int* __restrict__ col,
                                                        int* __restrict__ deg, int E) {
    int e = blockIdx.x * 256 + threadIdx.x;
    if (e < E) atomicAdd(&deg[col[e]], 1);
}

// per-block exclusive scan of deg (1024 elems/block) -> rowptr; block totals out
__global__ __launch_bounds__(256) void scan1_kernel(const int* __restrict__ deg,
                                                    int* __restrict__ rowptr,
                                                    int* __restrict__ blockSums, int N) {
    __shared__ int ts[256];
    const int t = threadIdx.x;
    const int base = blockIdx.x * 1024 + t * 4;
    int v0 = 0, v1 = 0, v2 = 0, v3 = 0;
    if (base + 3 < N) {
        int4 v = *(const int4*)&deg[base];
        v0 = v.x; v1 = v.y; v2 = v.z; v3 = v.w;
    } else {
        if (base + 0 < N) v0 = deg[base + 0];
        if (base + 1 < N) v1 = deg[base + 1];
        if (base + 2 < N) v2 = deg[base + 2];
        if (base + 3 < N) v3 = deg[base + 3];
    }
    const int tot = v0 + v1 + v2 + v3;
    ts[t] = tot;
    __syncthreads();
    for (int off = 1; off < 256; off <<= 1) {
        int add = (t >= off) ? ts[t - off] : 0;
        __syncthreads();
        ts[t] += add;
        __syncthreads();
    }
    const int excl = ts[t] - tot;   // exclusive prefix of this thread within block
    if (base + 0 < N) rowptr[base + 0] = excl;
    if (base + 1 < N) rowptr[base + 1] = excl + v0;
    if (base + 2 < N) rowptr[base + 2] = excl + v0 + v1;
    if (base + 3 < N) rowptr[base + 3] = excl + v0 + v1 + v2;
    if (t == 255) blockSums[blockIdx.x] = ts[255];
}

// single-block inclusive scan of blockSums -> blockOffs (B <= 128)
__global__ __launch_bounds__(128) void scan2_kernel(const int* __restrict__ blockSums,
                                                    int* __restrict__ blockOffs, int B) {
    __shared__ int ts[128];
    const int t = threadIdx.x;
    ts[t] = (t < B) ? blockSums[t] : 0;
    __syncthreads();
    for (int off = 1; off < 128; off <<= 1) {
        int add = (t >= off) ? ts[t - off] : 0;
        __syncthreads();
        ts[t] += add;
        __syncthreads();
    }
    if (t < B) blockOffs[t] = ts[t];
}

__global__ __launch_bounds__(256) void scan3_kernel(int* __restrict__ rowptr,
                                                    const int* __restrict__ blockOffs, int N) {
    int i = blockIdx.x * 256 + threadIdx.x;
    if (i >= N) return;
    int b = i >> 10;
    if (b > 0) rowptr[i] += blockOffs[b - 1];
}

__global__ __launch_bounds__(256) void dinv_kernel(int* __restrict__ degi,
                                                   float* __restrict__ dinv, int N) {
    int n = blockIdx.x * 256 + threadIdx.x;
    if (n < N) dinv[n] = 1.0f / sqrtf((float)degi[n] + 1.0f);  // +1 = self loop
}

// counting-sort fill. Uses the rowptr-shift trick: atomicAdd advances rowptr[c]
// to the bucket end; afterwards bucket c = [c==0?0:rowptr[c-1], rowptr[c]).
__global__ __launch_bounds__(256) void fill_kernel(const int* __restrict__ ei,
                                                   int* __restrict__ rowptr,
                                                   int* __restrict__ src_sorted, int E) {
    int e = blockIdx.x * 256 + threadIdx.x;
    if (e >= E) return;
    int c = ei[E + e];
    int pos = atomicAdd(&rowptr[c], 1);
    src_sorted[pos] = ei[e];
}

// T[N,128] = act(H[N,128]) @ W[128,128]; act = relu if applyRelu (deferred relu)
__global__ __launch_bounds__(256) void gemm128_kernel(const float* __restrict__ H,
                                                      const float* __restrict__ W,
                                                      float* __restrict__ T,
                                                      int N, int applyRelu) {
    __shared__ float Ws[64 * 128];
    __shared__ float xs[32 * 132];
    const int tid = threadIdx.x;
    const int row0 = blockIdx.x * 32;

    {
        const float4* H4 = (const float4*)H;
        #pragma unroll
        for (int i = 0; i < 4; ++i) {
            int lin = tid + i * 256;
            int r = lin >> 5;
            int k4 = lin & 31;
            int gr = row0 + r;
            float4 v = make_float4(0.f, 0.f, 0.f, 0.f);
            if (gr < N) v = H4[(size_t)gr * 32 + k4];
            if (applyRelu) {
                v.x = fmaxf(v.x, 0.f); v.y = fmaxf(v.y, 0.f);
                v.z = fmaxf(v.z, 0.f); v.w = fmaxf(v.w, 0.f);
            }
            *(float4*)&xs[r * 132 + k4 * 4] = v;
        }
    }

    const int c = (tid & 31) * 4;
    const int r0 = (tid >> 5) * 4;
    float acc[4][4];
    #pragma unroll
    for (int i = 0; i < 4; ++i)
        #pragma unroll
        for (int j = 0; j < 4; ++j) acc[i][j] = 0.f;

    for (int p = 0; p < 2; ++p) {
        __syncthreads();
        {
            const float4* W4 = (const float4*)(W + p * 64 * 128);
            float4* Ws4 = (float4*)Ws;
            #pragma unroll
            for (int i = 0; i < 8; ++i) Ws4[tid + i * 256] = W4[tid + i * 256];
        }
        __syncthreads();
        const int kbase = p * 64;
        #pragma unroll 4
        for (int k = 0; k < 64; k += 4) {
            float4 xv[4];
            #pragma unroll
            for (int i = 0; i < 4; ++i)
                xv[i] = *(const float4*)&xs[(r0 + i) * 132 + kbase + k];
            #pragma unroll
            for (int kk = 0; kk < 4; ++kk) {
                float4 wv = *(const float4*)&Ws[(k + kk) * 128 + c];
                #pragma unroll
                for (int i = 0; i < 4; ++i) {
                    float xk = (kk == 0) ? xv[i].x : (kk == 1) ? xv[i].y
                             : (kk == 2) ? xv[i].z : xv[i].w;
                    acc[i][0] = fmaf(xk, wv.x, acc[i][0]);
                    acc[i][1] = fmaf(xk, wv.y, acc[i][1]);
                    acc[i][2] = fmaf(xk, wv.z, acc[i][2]);
                    acc[i][3] = fmaf(xk, wv.w, acc[i][3]);
                }
            }
        }
    }
    #pragma unroll
    for (int i = 0; i < 4; ++i) {
        int gr = row0 + r0 + i;
        if (gr < N)
            *(float4*)&T[(size_t)gr * 128 + c] =
                make_float4(acc[i][0], acc[i][1], acc[i][2], acc[i][3]);
    }
}

// one wave per node: B[n,:] = dinv[n]^2*A[n,:] + bias + sum_e dinv[n]*dinv[s]*A[s,:]
__global__ __launch_bounds__(256) void agg_kernel(const int* __restrict__ rowptr,
                                                  const int* __restrict__ src,
                                                  const float* __restrict__ dinv,
                                                  const float* __restrict__ A,
                                                  const float* __restrict__ bias,
                                                  float* __restrict__ B, int N) {
    int w = (blockIdx.x * 256 + threadIdx.x) >> 6;
    if (w >= N) return;
    const int lane = threadIdx.x & 63;
    const int beg = (w > 0) ? rowptr[w - 1] : 0;   // rowptr-shift trick (post-fill)
    const int end = rowptr[w];
    const float dn = dinv[w];
    float2 a = ((const float2*)(A + (size_t)w * 128))[lane];
    float2 bv = ((const float2*)bias)[lane];
    float2 acc;
    acc.x = fmaf(dn * dn, a.x, bv.x);
    acc.y = fmaf(dn * dn, a.y, bv.y);
    int e = beg;
    for (; e + 1 < end; e += 2) {   // 2-way unroll to overlap gather latency
        int s0 = src[e], s1 = src[e + 1];
        float n0 = dn * dinv[s0], n1 = dn * dinv[s1];
        float2 v0 = ((const float2*)(A + (size_t)s0 * 128))[lane];
        float2 v1 = ((const float2*)(A + (size_t)s1 * 128))[lane];
        acc.x = fmaf(n0, v0.x, acc.x); acc.y = fmaf(n0, v0.y, acc.y);
        acc.x = fmaf(n1, v1.x, acc.x); acc.y = fmaf(n1, v1.y, acc.y);
    }
    if (e < end) {
        int s0 = src[e];
        float n0 = dn * dinv[s0];
        float2 v0 = ((const float2*)(A + (size_t)s0 * 128))[lane];
        acc.x = fmaf(n0, v0.x, acc.x); acc.y = fmaf(n0, v0.y, acc.y);
    }
    ((float2*)(B + (size_t)w * 128))[lane] = acc;
}

__device__ __forceinline__ int lower_bound_dev(const int* __restrict__ a, int n, int key) {
    int lo = 0, hi = n;
    while (lo < hi) {
        int mid = (lo + hi) >> 1;
        if (a[mid] < key) lo = mid + 1; else hi = mid;
    }
    return lo;
}

// one block per graph: out[g] = dot(mean_n relu(H[n,:]), lin_w) + lin_b
__global__ __launch_bounds__(256) void poolfinal_kernel(const float* __restrict__ H,
                                                        const int* __restrict__ batch,
                                                        const float* __restrict__ lin_w,
                                                        const float* __restrict__ lin_b,
                                                        float* __restrict__ out, int N) {
    const int g = blockIdx.x;
    const int lo = lower_bound_dev(batch, N, g);
    const int hi = lower_bound_dev(batch, N, g + 1);
    const int col = threadIdx.x & 127;
    const int half = threadIdx.x >> 7;
    float acc = 0.f;
    for (int n = lo + half; n < hi; n += 2)
        acc += fmaxf(H[(size_t)n * 128 + col], 0.f);
    __shared__ float red[256];
    red[threadIdx.x] = acc * lin_w[col];
    __syncthreads();
    for (int s = 128; s > 0; s >>= 1) {
        if (threadIdx.x < s) red[threadIdx.x] += red[threadIdx.x + s];
        __syncthreads();
    }
    if (threadIdx.x == 0) {
        float cnt = (float)(hi - lo);
        out[g] = red[0] / fmaxf(cnt, 1.0f) + lin_b[0];
    }
}

extern "C" void kernel_launch(void* const* d_in, const int* in_sizes, int n_in,
                              void* d_out, int out_size, void* d_ws, size_t ws_size,
                              hipStream_t stream) {
    const float* x     = (const float*)d_in[0];
    const int*   ei    = (const int*)d_in[1];    // [2,E]: rows then cols
    const int*   batch = (const int*)d_in[2];
    const float* W1    = (const float*)d_in[3];
    const float* b1    = (const float*)d_in[4];
    const float* W2    = (const float*)d_in[5];
    const float* b2    = (const float*)d_in[6];
    const float* W3    = (const float*)d_in[7];
    const float* b3    = (const float*)d_in[8];
    const float* lin_w = (const float*)d_in[9];
    const float* lin_b = (const float*)d_in[10];
    float* out = (float*)d_out;

    const int N = in_sizes[0] / 128;
    const int E = in_sizes[1] / 2;
    const int nBlk = (N + 1023) / 1024;          // scan blocks

    // workspace carve-up: A | B | deg(int) | dinv | rowptr | src_sorted | scan tmp
    float* A         = (float*)d_ws;
    float* B         = A + (size_t)N * 128;
    int*   deg       = (int*)(B + (size_t)N * 128);
    float* dinv      = (float*)(deg + N);
    int*   rowptr    = (int*)(dinv + N);
    int*   src_srt   = rowptr + N;
    int*   blockSums = src_srt + E;
    int*   blockOffs = blockSums + 256;

    // ---- CSR build (once per call, reused by all 3 layers) ----
    hipMemsetAsync(deg, 0, (size_t)N * sizeof(int), stream);
    count_deg_kernel<<<(E + 255) / 256, 256, 0, stream>>>(ei + E, deg, E);
    scan1_kernel<<<nBlk, 256, 0, stream>>>(deg, rowptr, blockSums, N);
    scan2_kernel<<<1, 128, 0, stream>>>(blockSums, blockOffs, nBlk);
    scan3_kernel<<<(N + 255) / 256, 256, 0, stream>>>(rowptr, blockOffs, N);
    dinv_kernel<<<(N + 255) / 256, 256, 0, stream>>>(deg, dinv, N);
    fill_kernel<<<(E + 255) / 256, 256, 0, stream>>>(ei, rowptr, src_srt, E);
    // after fill: bucket n = [n==0?0:rowptr[n-1], rowptr[n])

    const float* Ws[3] = {W1, W2, W3};
    const float* bs[3] = {b1, b2, b3};
    for (int l = 0; l < 3; ++l) {
        gemm128_kernel<<<(N + 31) / 32, 256, 0, stream>>>(l == 0 ? x : B, Ws[l], A, N,
                                                          l == 0 ? 0 : 1);
        agg_kernel<<<((size_t)N * 64 + 255) / 256, 256, 0, stream>>>(rowptr, src_srt,
                                                                     dinv, A, bs[l], B, N);
    }

    poolfinal_kernel<<<64, 256, 0, stream>>>(B, batch, lin_w, lin_b, out, N);
}